// Round 1
// baseline (693.219 us; speedup 1.0000x reference)
//
#include <hip/hip_runtime.h>

#define D 256
#define C 128

__device__ __forceinline__ float waveAllSum(float v) {
  #pragma unroll
  for (int m = 1; m < 64; m <<= 1) v += __shfl_xor(v, m, 64);
  return v;
}

__global__ void zero_ws_kernel(float* __restrict__ ws, int n) {
  int i = blockIdx.x * blockDim.x + threadIdx.x;
  if (i < n) ws[i] = 0.f;
}

// One wave processes one row per iteration: 64 lanes x float4 = 256 floats.
// LDS accumulator layout is element-transposed: natural element e of class c
// lives at lsum[c*D + (e&3)*64 + (e>>2)], so each ds_add_f32 hits banks
// lane%32 (2-way aliasing = free) instead of 8-way conflicts.
__global__ __launch_bounds__(1024) void accum_kernel(
    const float* __restrict__ dirs, const int* __restrict__ labels,
    float* __restrict__ g_sums, float* __restrict__ g_cnts, int B) {
  __shared__ float lsum[C * D];   // 128 KB
  __shared__ float lcnt[C];
  const int tid = threadIdx.x;
  for (int i = tid; i < C * D; i += 1024) lsum[i] = 0.f;
  if (tid < C) lcnt[tid] = 0.f;
  __syncthreads();

  const int lane = tid & 63;
  const int wid  = tid >> 6;
  const int nw   = 1024 >> 6;   // 16 waves
  const int rpb  = (B + gridDim.x - 1) / gridDim.x;
  const int r0   = blockIdx.x * rpb;
  const int r1   = min(B, r0 + rpb);

  for (int r = r0 + wid; r < r1; r += nw) {
    float4 v = ((const float4*)(dirs + (size_t)r * D))[lane];
    float ss = v.x * v.x + v.y * v.y + v.z * v.z + v.w * v.w;
    ss = waveAllSum(ss);
    float inv = 1.f / fmaxf(sqrtf(ss), 1e-12f);
    int c = labels[r];
    float* base = lsum + c * D;
    atomicAdd(base + lane,        v.x * inv);
    atomicAdd(base + 64  + lane,  v.y * inv);
    atomicAdd(base + 128 + lane,  v.z * inv);
    atomicAdd(base + 192 + lane,  v.w * inv);
    if (lane == 0) atomicAdd(&lcnt[c], 1.f);
  }
  __syncthreads();

  // Merge block-private sums into the global accumulator (L2-resident).
  for (int i = tid; i < C * D; i += 1024) {
    float s = lsum[i];
    if (s != 0.f) atomicAdd(&g_sums[i], s);
  }
  if (tid < C) {
    float s = lcnt[tid];
    if (s != 0.f) atomicAdd(&g_cnts[tid], s);
  }
}

// Single block: EMA update + renormalize + where(), writes new_v, and the
// loss via  sum_i cos_i = sum_c dot(sums_c, new_v_c).
__global__ __launch_bounds__(256) void finalize_kernel(
    const float* __restrict__ g_sums, const float* __restrict__ g_cnts,
    const float* __restrict__ v_class, const int* __restrict__ step_ptr,
    float* __restrict__ out, int B) {
  const int lane = threadIdx.x & 63;
  const int wid  = threadIdx.x >> 6;   // 0..3
  const float stepf = (float)step_ptr[0];
  const float alpha = fminf(0.02f, stepf / (stepf + 50.f));
  float S = 0.f;

  for (int c = wid; c < C; c += 4) {
    float cnt   = g_cnts[c];
    float denom = fmaxf(cnt, 1.f);
    float s[4], vc[4], bm[4];
    float nb = 0.f;
    #pragma unroll
    for (int j = 0; j < 4; j++) {
      int e = lane + 64 * j;
      s[j]  = g_sums[c * D + ((e & 3) << 6) + (e >> 2)];  // unpermute
      vc[j] = v_class[c * D + e];
      bm[j] = s[j] / denom;
      nb += bm[j] * bm[j];
    }
    nb = waveAllSum(nb);
    float invnb = 1.f / fmaxf(sqrtf(nb), 1e-12f);
    float u[4];
    float nu = 0.f;
    #pragma unroll
    for (int j = 0; j < 4; j++) {
      u[j] = (1.f - alpha) * vc[j] + alpha * (bm[j] * invnb);
      nu += u[j] * u[j];
    }
    nu = waveAllSum(nu);
    float invnu = 1.f / fmaxf(sqrtf(nu), 1e-12f);
    #pragma unroll
    for (int j = 0; j < 4; j++) {
      int e = lane + 64 * j;
      float nv = (cnt > 0.f) ? u[j] * invnu : vc[j];
      out[1 + c * D + e] = nv;
      S += s[j] * nv;
    }
  }

  S = waveAllSum(S);
  __shared__ float partS[4];
  if (lane == 0) partS[wid] = S;
  __syncthreads();
  if (threadIdx.x == 0) {
    float tot = partS[0] + partS[1] + partS[2] + partS[3];
    out[0] = 0.1f * (1.f - tot / (float)B);
  }
}

extern "C" void kernel_launch(void* const* d_in, const int* in_sizes, int n_in,
                              void* d_out, int out_size, void* d_ws, size_t ws_size,
                              hipStream_t stream) {
  const float* dirs    = (const float*)d_in[0];
  const float* v_class = (const float*)d_in[1];
  const int*   labels  = (const int*)d_in[2];
  const int*   step    = (const int*)d_in[3];
  const int B = in_sizes[2];

  float* g_sums = (float*)d_ws;
  float* g_cnts = g_sums + C * D;
  const int nz = C * D + C;

  zero_ws_kernel<<<(nz + 255) / 256, 256, 0, stream>>>(g_sums, nz);
  accum_kernel<<<256, 1024, 0, stream>>>(dirs, labels, g_sums, g_cnts, B);
  finalize_kernel<<<1, 256, 0, stream>>>(g_sums, g_cnts, v_class, step,
                                         (float*)d_out, B);
}

// Round 6
// 427.298 us; speedup vs baseline: 1.6223x; 1.6223x over previous
//
#include <hip/hip_runtime.h>

// PrototypeField: one-pass streaming implementation.
//   pass 1 (pf_accum): normalize rows, fixed-point segment-sum into LDS,
//                      merge to global via native i32 atomics.
//   pass 2 (pf_final): EMA + renorm + where(); loss via
//                      sum_i cos_i == sum_c dot(sums_c, new_v_c).

#define PF_D 256
#define PF_C 128
#define PF_SCALE 524288.0f            // 2^19 fixed-point quantum
#define PF_INV_SCALE (1.0f / 524288.0f)

__device__ __forceinline__ float pf_wave_sum(float v) {
  #pragma unroll
  for (int m = 1; m < 64; m <<= 1) v += __shfl_xor(v, m, 64);
  return v;
}

__global__ void pf_zero(int* __restrict__ ws, int n) {
  int i = blockIdx.x * blockDim.x + threadIdx.x;
  if (i < n) ws[i] = 0;
}

// One wave handles one row per iteration: 64 lanes x float4 == 256 floats.
// The LDS accumulator is i32 fixed-point so every add is a native ds_add_u32
// (no FP compare-and-swap loop). Elements are stored transposed —
// element e of class c lives at lacc[c*PF_D + (e&3)*64 + (e>>2)] — so a
// wave's 64 lanes map to banks lane%32 (2-way aliasing, which is free).
__global__ __launch_bounds__(1024) void pf_accum(
    const float* __restrict__ dirs, const int* __restrict__ labels,
    int* __restrict__ gsum, int* __restrict__ gcnt, int B) {
  __shared__ int lacc[PF_C * PF_D];   // 128 KiB
  __shared__ int lnum[PF_C];
  const int tid = threadIdx.x;
  for (int i = tid; i < PF_C * PF_D; i += 1024) lacc[i] = 0;
  if (tid < PF_C) lnum[tid] = 0;
  __syncthreads();

  const int lane = tid & 63;
  const int wave = tid >> 6;          // 0..15
  const int rows_per_block = (B + (int)gridDim.x - 1) / (int)gridDim.x;
  const int row_lo = blockIdx.x * rows_per_block;
  const int row_hi = min(B, row_lo + rows_per_block);

  for (int r = row_lo + wave; r < row_hi; r += 16) {
    float4 v = ((const float4*)(dirs + (size_t)r * PF_D))[lane];
    float sq = v.x * v.x + v.y * v.y + v.z * v.z + v.w * v.w;
    sq = pf_wave_sum(sq);
    float k = PF_SCALE / fmaxf(sqrtf(sq), 1e-12f);
    int cls = labels[r];
    int* p = lacc + cls * PF_D;
    atomicAdd(p + lane,       __float2int_rn(v.x * k));
    atomicAdd(p + 64  + lane, __float2int_rn(v.y * k));
    atomicAdd(p + 128 + lane, __float2int_rn(v.z * k));
    atomicAdd(p + 192 + lane, __float2int_rn(v.w * k));
    if (lane == 0) atomicAdd(&lnum[cls], 1);
  }
  __syncthreads();

  // Fold the block-private accumulator into the global one (i32 atomics,
  // L2-resident: 32K distinct addresses).
  for (int i = tid; i < PF_C * PF_D; i += 1024) {
    int s = lacc[i];
    if (s != 0) atomicAdd(&gsum[i], s);
  }
  if (tid < PF_C) {
    int s = lnum[tid];
    if (s != 0) atomicAdd(&gcnt[tid], s);
  }
}

// Single 256-thread block: per-class EMA update, renormalize, where();
// writes new_v and the scalar loss.
__global__ __launch_bounds__(256) void pf_final(
    const int* __restrict__ gsum, const int* __restrict__ gcnt,
    const float* __restrict__ v_class, const int* __restrict__ step_ptr,
    float* __restrict__ out, int B) {
  const int lane = threadIdx.x & 63;
  const int wave = threadIdx.x >> 6;   // 0..3
  const float stepf = (float)step_ptr[0];
  const float alpha = fminf(0.02f, stepf / (stepf + 50.f));
  float acc = 0.f;

  for (int c = wave; c < PF_C; c += 4) {
    int   cnt   = gcnt[c];
    float denom = fmaxf((float)cnt, 1.f);
    float s[4], vc[4], bm[4];
    float nb = 0.f;
    #pragma unroll
    for (int j = 0; j < 4; j++) {
      int e = lane + 64 * j;
      s[j]  = (float)gsum[c * PF_D + ((e & 3) << 6) + (e >> 2)] * PF_INV_SCALE;
      vc[j] = v_class[c * PF_D + e];
      bm[j] = s[j] / denom;
      nb += bm[j] * bm[j];
    }
    nb = pf_wave_sum(nb);
    float rb = 1.f / fmaxf(sqrtf(nb), 1e-12f);
    float u[4];
    float nu = 0.f;
    #pragma unroll
    for (int j = 0; j < 4; j++) {
      u[j] = (1.f - alpha) * vc[j] + alpha * (bm[j] * rb);
      nu += u[j] * u[j];
    }
    nu = pf_wave_sum(nu);
    float ru = 1.f / fmaxf(sqrtf(nu), 1e-12f);
    #pragma unroll
    for (int j = 0; j < 4; j++) {
      int e = lane + 64 * j;
      float nv = (cnt > 0) ? u[j] * ru : vc[j];
      out[1 + c * PF_D + e] = nv;
      acc += s[j] * nv;
    }
  }

  acc = pf_wave_sum(acc);
  __shared__ float part[4];
  if (lane == 0) part[wave] = acc;
  __syncthreads();
  if (threadIdx.x == 0) {
    float tot = part[0] + part[1] + part[2] + part[3];
    out[0] = 0.1f * (1.f - tot / (float)B);
  }
}

extern "C" void kernel_launch(void* const* d_in, const int* in_sizes, int n_in,
                              void* d_out, int out_size, void* d_ws, size_t ws_size,
                              hipStream_t stream) {
  const float* dirs    = (const float*)d_in[0];
  const float* v_class = (const float*)d_in[1];
  const int*   labels  = (const int*)d_in[2];
  const int*   step    = (const int*)d_in[3];
  const int B = in_sizes[2];

  int* gsum = (int*)d_ws;
  int* gcnt = gsum + PF_C * PF_D;
  const int nzero = PF_C * PF_D + PF_C;

  pf_zero<<<(nzero + 255) / 256, 256, 0, stream>>>(gsum, nzero);
  pf_accum<<<256, 1024, 0, stream>>>(dirs, labels, gsum, gcnt, B);
  pf_final<<<1, 256, 0, stream>>>(gsum, gcnt, v_class, step,
                                  (float*)d_out, B);
}

// Round 7
// 390.308 us; speedup vs baseline: 1.7761x; 1.0948x over previous
//
#include <hip/hip_runtime.h>

// PrototypeField: one-pass streaming implementation, i32 fixed-point atomics.
//   pf_accum: 4-row-ILP normalize + LDS segment-sum, merge via global i32 atomics.
//   pf_cls:   one block per class: EMA + renorm + where(); per-class dot partial.
//   pf_loss:  reduce 128 dots -> scalar loss.

#define PF_D 256
#define PF_C 128
#define PF_SCALE 524288.0f            // 2^19 fixed-point quantum
#define PF_INV_SCALE (1.0f / 524288.0f)

__device__ __forceinline__ float pf_wave_sum(float v) {
  #pragma unroll
  for (int m = 1; m < 64; m <<= 1) v += __shfl_xor(v, m, 64);
  return v;
}

__global__ void pf_zero(int* __restrict__ ws, int n) {
  int i = blockIdx.x * blockDim.x + threadIdx.x;
  if (i < n) ws[i] = 0;
}

// One wave handles 4 rows per iteration (independent loads overlap the ~900cy
// HBM latency; interleaved butterflies overlap the shuffle chains).
// 64 lanes x float4 == one 256-float row. LDS accumulator is i32 fixed-point
// (native ds_add_u32). Element-transposed layout: element e of class c lives
// at lacc[c*PF_D + (e&3)*64 + (e>>2)] so lanes map to banks lane%32
// (2-way aliasing = free).
__global__ __launch_bounds__(1024) void pf_accum(
    const float* __restrict__ dirs, const int* __restrict__ labels,
    int* __restrict__ gsum, int* __restrict__ gcnt, int B) {
  __shared__ int lacc[PF_C * PF_D];   // 128 KiB
  __shared__ int lnum[PF_C];
  const int tid = threadIdx.x;
  for (int i = tid; i < PF_C * PF_D; i += 1024) lacc[i] = 0;
  if (tid < PF_C) lnum[tid] = 0;
  __syncthreads();

  const int lane = tid & 63;
  const int wave = tid >> 6;          // 0..15
  const int rows_per_block = (B + (int)gridDim.x - 1) / (int)gridDim.x;
  const int row_lo = blockIdx.x * rows_per_block;
  const int row_hi = min(B, row_lo + rows_per_block);
  const int rows_per_wave = (rows_per_block + 15) >> 4;
  const int w_lo = row_lo + wave * rows_per_wave;
  const int w_hi = min(row_hi, w_lo + rows_per_wave);

  int r = w_lo;
  for (; r + 4 <= w_hi; r += 4) {
    float4 v0 = ((const float4*)(dirs + (size_t)(r + 0) * PF_D))[lane];
    float4 v1 = ((const float4*)(dirs + (size_t)(r + 1) * PF_D))[lane];
    float4 v2 = ((const float4*)(dirs + (size_t)(r + 2) * PF_D))[lane];
    float4 v3 = ((const float4*)(dirs + (size_t)(r + 3) * PF_D))[lane];
    int c0 = labels[r + 0], c1 = labels[r + 1];
    int c2 = labels[r + 2], c3 = labels[r + 3];
    float s0 = v0.x * v0.x + v0.y * v0.y + v0.z * v0.z + v0.w * v0.w;
    float s1 = v1.x * v1.x + v1.y * v1.y + v1.z * v1.z + v1.w * v1.w;
    float s2 = v2.x * v2.x + v2.y * v2.y + v2.z * v2.z + v2.w * v2.w;
    float s3 = v3.x * v3.x + v3.y * v3.y + v3.z * v3.z + v3.w * v3.w;
    #pragma unroll
    for (int m = 1; m < 64; m <<= 1) {
      s0 += __shfl_xor(s0, m, 64);
      s1 += __shfl_xor(s1, m, 64);
      s2 += __shfl_xor(s2, m, 64);
      s3 += __shfl_xor(s3, m, 64);
    }
    float k0 = PF_SCALE / fmaxf(sqrtf(s0), 1e-12f);
    float k1 = PF_SCALE / fmaxf(sqrtf(s1), 1e-12f);
    float k2 = PF_SCALE / fmaxf(sqrtf(s2), 1e-12f);
    float k3 = PF_SCALE / fmaxf(sqrtf(s3), 1e-12f);
    int* p0 = lacc + c0 * PF_D;
    int* p1 = lacc + c1 * PF_D;
    int* p2 = lacc + c2 * PF_D;
    int* p3 = lacc + c3 * PF_D;
    atomicAdd(p0 + lane,       __float2int_rn(v0.x * k0));
    atomicAdd(p1 + lane,       __float2int_rn(v1.x * k1));
    atomicAdd(p2 + lane,       __float2int_rn(v2.x * k2));
    atomicAdd(p3 + lane,       __float2int_rn(v3.x * k3));
    atomicAdd(p0 + 64 + lane,  __float2int_rn(v0.y * k0));
    atomicAdd(p1 + 64 + lane,  __float2int_rn(v1.y * k1));
    atomicAdd(p2 + 64 + lane,  __float2int_rn(v2.y * k2));
    atomicAdd(p3 + 64 + lane,  __float2int_rn(v3.y * k3));
    atomicAdd(p0 + 128 + lane, __float2int_rn(v0.z * k0));
    atomicAdd(p1 + 128 + lane, __float2int_rn(v1.z * k1));
    atomicAdd(p2 + 128 + lane, __float2int_rn(v2.z * k2));
    atomicAdd(p3 + 128 + lane, __float2int_rn(v3.z * k3));
    atomicAdd(p0 + 192 + lane, __float2int_rn(v0.w * k0));
    atomicAdd(p1 + 192 + lane, __float2int_rn(v1.w * k1));
    atomicAdd(p2 + 192 + lane, __float2int_rn(v2.w * k2));
    atomicAdd(p3 + 192 + lane, __float2int_rn(v3.w * k3));
    if (lane < 4) {
      int cc = (lane == 0) ? c0 : (lane == 1) ? c1 : (lane == 2) ? c2 : c3;
      atomicAdd(&lnum[cc], 1);
    }
  }
  // Tail (dead for the bench shape: 64 rows/wave is a multiple of 4).
  for (; r < w_hi; r++) {
    float4 v = ((const float4*)(dirs + (size_t)r * PF_D))[lane];
    float sq = pf_wave_sum(v.x * v.x + v.y * v.y + v.z * v.z + v.w * v.w);
    float k = PF_SCALE / fmaxf(sqrtf(sq), 1e-12f);
    int cls = labels[r];
    int* p = lacc + cls * PF_D;
    atomicAdd(p + lane,       __float2int_rn(v.x * k));
    atomicAdd(p + 64  + lane, __float2int_rn(v.y * k));
    atomicAdd(p + 128 + lane, __float2int_rn(v.z * k));
    atomicAdd(p + 192 + lane, __float2int_rn(v.w * k));
    if (lane == 0) atomicAdd(&lnum[cls], 1);
  }
  __syncthreads();

  // Fold the block-private accumulator into the global one (i32 atomics,
  // 32K distinct L2-resident addresses).
  for (int i = tid; i < PF_C * PF_D; i += 1024) {
    int s = lacc[i];
    if (s != 0) atomicAdd(&gsum[i], s);
  }
  if (tid < PF_C) {
    int s = lnum[tid];
    if (s != 0) atomicAdd(&gcnt[tid], s);
  }
}

// One wave (block) per class: EMA + renormalize + where(); writes new_v and
// the per-class dot partial  dot(sums_c, new_v_c).
__global__ __launch_bounds__(64) void pf_cls(
    const int* __restrict__ gsum, const int* __restrict__ gcnt,
    const float* __restrict__ v_class, const int* __restrict__ step_ptr,
    float* __restrict__ out, float* __restrict__ dots) {
  const int c = blockIdx.x;
  const int lane = threadIdx.x;
  const float stepf = (float)step_ptr[0];
  const float alpha = fminf(0.02f, stepf / (stepf + 50.f));

  const int cnt = gcnt[c];
  const float denom = fmaxf((float)cnt, 1.f);
  float s[4], vc[4], bm[4];
  float nb = 0.f;
  #pragma unroll
  for (int j = 0; j < 4; j++) {
    int e = lane + 64 * j;
    s[j]  = (float)gsum[c * PF_D + ((e & 3) << 6) + (e >> 2)] * PF_INV_SCALE;
    vc[j] = v_class[c * PF_D + e];
    bm[j] = s[j] / denom;
    nb += bm[j] * bm[j];
  }
  nb = pf_wave_sum(nb);
  const float rb = 1.f / fmaxf(sqrtf(nb), 1e-12f);
  float u[4];
  float nu = 0.f;
  #pragma unroll
  for (int j = 0; j < 4; j++) {
    u[j] = (1.f - alpha) * vc[j] + alpha * (bm[j] * rb);
    nu += u[j] * u[j];
  }
  nu = pf_wave_sum(nu);
  const float ru = 1.f / fmaxf(sqrtf(nu), 1e-12f);
  float dacc = 0.f;
  #pragma unroll
  for (int j = 0; j < 4; j++) {
    int e = lane + 64 * j;
    float nv = (cnt > 0) ? u[j] * ru : vc[j];
    out[1 + c * PF_D + e] = nv;
    dacc += s[j] * nv;
  }
  dacc = pf_wave_sum(dacc);
  if (lane == 0) dots[c] = dacc;
}

__global__ __launch_bounds__(128) void pf_loss(
    const float* __restrict__ dots, float* __restrict__ out, int B) {
  const int tid = threadIdx.x;
  float v = dots[tid];                       // 128 threads == PF_C
  v = pf_wave_sum(v);
  __shared__ float part[2];
  if ((tid & 63) == 0) part[tid >> 6] = v;
  __syncthreads();
  if (tid == 0) out[0] = 0.1f * (1.f - (part[0] + part[1]) / (float)B);
}

extern "C" void kernel_launch(void* const* d_in, const int* in_sizes, int n_in,
                              void* d_out, int out_size, void* d_ws, size_t ws_size,
                              hipStream_t stream) {
  const float* dirs    = (const float*)d_in[0];
  const float* v_class = (const float*)d_in[1];
  const int*   labels  = (const int*)d_in[2];
  const int*   step    = (const int*)d_in[3];
  const int B = in_sizes[2];

  int*   gsum = (int*)d_ws;
  int*   gcnt = gsum + PF_C * PF_D;
  float* dots = (float*)(gcnt + PF_C);
  const int nzero = PF_C * PF_D + PF_C;

  pf_zero<<<(nzero + 255) / 256, 256, 0, stream>>>(gsum, nzero);
  pf_accum<<<256, 1024, 0, stream>>>(dirs, labels, gsum, gcnt, B);
  pf_cls<<<PF_C, 64, 0, stream>>>(gsum, gcnt, v_class, step,
                                  (float*)d_out, dots);
  pf_loss<<<1, 128, 0, stream>>>(dots, (float*)d_out, B);
}